// Round 10
// baseline (554.693 us; speedup 1.0000x reference)
//
#include <hip/hip_runtime.h>

// NeuralODE: y' = tanh(y@W1+b1)@W2+b2, fixed-step Dopri5, <=48 static iters.
// R11: R7b eval body EXACTLY (R9/R10 proved it locally optimal) + overlap
// boost: 8-OUTPUT-ROW blocks computing 16 rows redundantly. grid 1024 ->
// 4 blocks/CU (was 2). Block b computes rows [8b, 8b+16) identically to R7b
// (full 16-row MFMA tiles, same serial path) but outputs only [8b, 8b+8);
// upper half duplicates neighbor block's work. Latency-bound => redundant
// work rides in idle issue slots; co-residency doubles. VGPR 96 -> 5 w/SIMD
// cap, 16 waves/CU OK; LDS 4 x 9.7KB OK. Loads row-clamped at 8191.

typedef __attribute__((ext_vector_type(8))) short short8;  // 8 bf16 = 4 VGPRs
typedef __attribute__((ext_vector_type(4))) float f32x4;

#define SL 136  // LDS row stride in bf16: 272B = 16B-aligned rows (b128 reads)

__device__ __forceinline__ short f2bf(float f) {
  union { float f; unsigned u; } v; v.f = f;
  return (short)((v.u + 0x8000u) >> 16);  // for weight load only (not hot)
}

__device__ __forceinline__ float fast_tanh(float x) {
  // tanh(x) = 1 - 2/(exp2(c*x)+1), c = 2*log2(e). 5 VALU ops, exact at +-inf.
  float e = __builtin_amdgcn_exp2f(x * 2.88539008177793f);
  float r = __builtin_amdgcn_rcpf(e + 1.0f);
  return __builtin_fmaf(-2.0f, r, 1.0f);
}

// pack 2 f32 -> 2 bf16 in one instr; store lo/hi halves to two LDS addrs
// (compiler folds the hi store to ds_write_b16_d16_hi).
__device__ __forceinline__ void store_bf16_pair(short* p0, short* p1,
                                                float a, float b) {
  unsigned u;
  asm("v_cvt_pk_bf16_f32 %0, %1, %2" : "=v"(u) : "v"(a), "v"(b));
  *p0 = (short)(u & 0xffffu);
  *p1 = (short)(u >> 16);
}

__global__ __launch_bounds__(256, 4)
void node_kernel(const float* __restrict__ tptr, const float* __restrict__ x,
                 const float* __restrict__ W1, const float* __restrict__ b1,
                 const float* __restrict__ W2, const float* __restrict__ b2,
                 float* __restrict__ out) {
  const int tid  = threadIdx.x;
  const int wv   = tid >> 6;      // wave id (0..3); wave owns col-tiles 2wv,2wv+1
  const int lane = tid & 63;
  const int q    = lane >> 4;     // quad within wave
  const int colL = lane & 15;     // col within tile (C layout) / m row (A frag)
  const int blockRow = blockIdx.x * 8;   // 8 OUTPUT rows; computes 16

  __shared__ short A1[16][SL];   // staged y' (bf16, A-operand layout)
  __shared__ short A2[16][SL];   // staged tanh hidden (bf16)
  __shared__ float sred[256];

  // ---------- weight B-fragments (bf16) + biases into registers ----------
  // B-frag 16x16x32: lane holds B[k = kt*32 + quad*8 + i][n], i=0..7.
  short8 w1f[2][4], w2f[2][4];
  float b1v[2], b2v[2];
  int ncol[2];
#pragma unroll
  for (int j = 0; j < 2; ++j) {
    const int n = (2 * wv + j) * 16 + colL;
    ncol[j] = n;
    b1v[j] = b1[n]; b2v[j] = b2[n];
#pragma unroll
    for (int kt = 0; kt < 4; ++kt) {
      short8 v1, v2;
#pragma unroll
      for (int i = 0; i < 8; ++i) {
        const int k = kt * 32 + q * 8 + i;
        v1[i] = f2bf(W1[k * 128 + n]);
        v2[i] = f2bf(W2[k * 128 + n]);
      }
      w1f[j][kt] = v1; w2f[j][kt] = v2;
    }
  }

  // ---------- block-wide sum (256 threads) ----------
  auto block_sum = [&](float v) -> float {
    sred[tid] = v;
    __syncthreads();
    if (tid < 64) {
      float s = sred[tid] + sred[tid + 64] + sred[tid + 128] + sred[tid + 192];
#pragma unroll
      for (int o = 32; o > 0; o >>= 1) s += __shfl_down(s, o, 64);
      if (tid == 0) sred[0] = s;
    }
    __syncthreads();
    float r = sred[0];
    __syncthreads();
    return r;
  };

  // hoisted LDS addresses (constant immediate offsets thereafter)
  short* const wr1 = &A1[q * 4][0];
  short* const wr2 = &A2[q * 4][0];
  const short* const rd1 = &A1[colL][q * 8];
  const short* const rd2 = &A2[colL][q * 8];

  // ---------- one f-eval: LDS round-trip transpose + 2 MFMA layers ----------
  auto evalF = [&](auto&& gen, f32x4 (&fout)[2]) {
#pragma unroll
    for (int j = 0; j < 2; ++j) {
      f32x4 v = gen(j);
      store_bf16_pair(&wr1[0 * SL + ncol[j]], &wr1[1 * SL + ncol[j]], v[0], v[1]);
      store_bf16_pair(&wr1[2 * SL + ncol[j]], &wr1[3 * SL + ncol[j]], v[2], v[3]);
    }
    __syncthreads();
    short8 af[4];
#pragma unroll
    for (int kt = 0; kt < 4; ++kt) af[kt] = *(const short8*)(rd1 + kt * 32);
    f32x4 acc0 = {b1v[0], b1v[0], b1v[0], b1v[0]};
    f32x4 acc1 = {b1v[1], b1v[1], b1v[1], b1v[1]};
    __builtin_amdgcn_s_setprio(1);
#pragma unroll
    for (int kt = 0; kt < 4; ++kt) {
      acc0 = __builtin_amdgcn_mfma_f32_16x16x32_bf16(af[kt], w1f[0][kt], acc0, 0, 0, 0);
      acc1 = __builtin_amdgcn_mfma_f32_16x16x32_bf16(af[kt], w1f[1][kt], acc1, 0, 0, 0);
    }
    __builtin_amdgcn_s_setprio(0);
    {
      float h0a = fast_tanh(acc0[0]), h1a = fast_tanh(acc0[1]);
      float h2a = fast_tanh(acc0[2]), h3a = fast_tanh(acc0[3]);
      store_bf16_pair(&wr2[0 * SL + ncol[0]], &wr2[1 * SL + ncol[0]], h0a, h1a);
      store_bf16_pair(&wr2[2 * SL + ncol[0]], &wr2[3 * SL + ncol[0]], h2a, h3a);
      float h0b = fast_tanh(acc1[0]), h1b = fast_tanh(acc1[1]);
      float h2b = fast_tanh(acc1[2]), h3b = fast_tanh(acc1[3]);
      store_bf16_pair(&wr2[0 * SL + ncol[1]], &wr2[1 * SL + ncol[1]], h0b, h1b);
      store_bf16_pair(&wr2[2 * SL + ncol[1]], &wr2[3 * SL + ncol[1]], h2b, h3b);
    }
    __syncthreads();
#pragma unroll
    for (int kt = 0; kt < 4; ++kt) af[kt] = *(const short8*)(rd2 + kt * 32);
    f32x4 f0 = {b2v[0], b2v[0], b2v[0], b2v[0]};
    f32x4 f1 = {b2v[1], b2v[1], b2v[1], b2v[1]};
    __builtin_amdgcn_s_setprio(1);
#pragma unroll
    for (int kt = 0; kt < 4; ++kt) {
      f0 = __builtin_amdgcn_mfma_f32_16x16x32_bf16(af[kt], w2f[0][kt], f0, 0, 0, 0);
      f1 = __builtin_amdgcn_mfma_f32_16x16x32_bf16(af[kt], w2f[1][kt], f1, 0, 0, 0);
    }
    __builtin_amdgcn_s_setprio(0);
    fout[0] = f0; fout[1] = f1;
  };

  // ---------- dt0 via the MFMA evalF on row-0-broadcast state ----------
  float y0j[2], scl[2];
#pragma unroll
  for (int j = 0; j < 2; ++j) {
    y0j[j] = x[ncol[j]];
    scl[j] = 1.4e-8f + fabsf(y0j[j]) * 1.4e-8f;
  }
  f32x4 fb[2];
  evalF([&](int j) { float v = y0j[j]; return (f32x4){v, v, v, v}; }, fb);
  float f0j[2] = {fb[0][0], fb[1][0]};
  float t0 = 0.f, t1 = 0.f;
  if (q == 0) {
#pragma unroll
    for (int j = 0; j < 2; ++j) {
      float a = y0j[j] / scl[j]; t0 += a * a;
      float b = f0j[j] / scl[j]; t1 += b * b;
    }
  }
  float d0 = sqrtf(block_sum(t0));
  float d1 = sqrtf(block_sum(t1));
  float h0 = (d0 < 1e-5f || d1 < 1e-5f) ? 1e-6f : 0.01f * d0 / d1;
  evalF([&](int j) { float v = y0j[j] + h0 * f0j[j]; return (f32x4){v, v, v, v}; }, fb);
  float t2 = 0.f;
  if (q == 0) {
#pragma unroll
    for (int j = 0; j < 2; ++j) {
      float a = (fb[j][0] - f0j[j]) / scl[j]; t2 += a * a;
    }
  }
  float d2 = sqrtf(block_sum(t2)) / h0;
  float h1 = (d1 <= 1e-15f && d2 <= 1e-15f) ? fmaxf(1e-6f, h0 * 1e-3f)
                                            : powf(0.01f / (d1 + d2), 0.2f);
  const float dt0v = fminf(100.f * h0, h1);

  // ---------- load state y (rows clamped; upper 8 rows are redundant) ------
  f32x4 yr[2];
#pragma unroll
  for (int j = 0; j < 2; ++j)
#pragma unroll
    for (int r = 0; r < 4; ++r) {
      int row = blockRow + q * 4 + r;
      row = row < 8191 ? row : 8191;
      yr[j][r] = x[row * 128 + ncol[j]];
    }

  // ---------- main fixed-step Dopri5 loop ----------
  const float T = tptr[0] / 10.0f;  // t[0] / TIMESCALE
  float tt = 0.f;
  f32x4 k1[2], k2[2], k3[2], k4[2], k5[2], k6[2];

#pragma unroll 1
  for (int it = 0; it < 48; ++it) {
    float dt = fminf(fmaxf(T - tt, 0.f), dt0v);
    if (dt <= 0.f) break;  // uniform across threads and blocks; tt only grows
    evalF([&](int j) { return yr[j]; }, k1);
    {
      const float c1 = dt * 0.2f;
      evalF([&](int j) { return yr[j] + c1 * k1[j]; }, k2);
    }
    {
      const float c1 = dt * 0.075f, c2 = dt * 0.225f;
      evalF([&](int j) { return yr[j] + c1 * k1[j] + c2 * k2[j]; }, k3);
    }
    {
      const float c1 = dt * 0.9777777777777777f, c2 = dt * -3.7333333333333334f,
                  c3 = dt * 3.5555555555555554f;
      evalF([&](int j) { return yr[j] + c1 * k1[j] + c2 * k2[j] + c3 * k3[j]; }, k4);
    }
    {
      const float c1 = dt * 2.9525986892242035f, c2 = dt * -11.595793324188385f,
                  c3 = dt * 9.822892851699436f, c4 = dt * -0.2908093278463649f;
      evalF([&](int j) {
        return yr[j] + c1 * k1[j] + c2 * k2[j] + c3 * k3[j] + c4 * k4[j];
      }, k5);
    }
    {
      const float c1 = dt * 2.8462752525252526f, c2 = dt * -10.757575757575758f,
                  c3 = dt * 8.906422717743473f, c4 = dt * 0.2784090909090909f,
                  c5 = dt * -0.27351165254237287f;
      evalF([&](int j) {
        return yr[j] + c1 * k1[j] + c2 * k2[j] + c3 * k3[j] + c4 * k4[j]
                     + c5 * k5[j];
      }, k6);
    }
    {
      const float c1 = dt * 0.0911458333333333f, c3 = dt * 0.449236298292902f,
                  c4 = dt * 0.6510416666666666f, c5 = dt * -0.32237617924528303f,
                  c6 = dt * 0.13095238095238096f;
#pragma unroll
      for (int j = 0; j < 2; ++j)
        yr[j] = yr[j] + c1 * k1[j] + c3 * k3[j] + c4 * k4[j] + c5 * k5[j]
                      + c6 * k6[j];
    }
    tt += dt;
  }

  // ---------- epilogue: out = stack([x, yT]) -- 8 output rows ----------
  {
    const float4* x4 = (const float4*)(x + blockRow * 128);
    float4* o4 = (float4*)(out + blockRow * 128);
    o4[tid] = x4[tid];              // 8 rows * 128 f32 = 256 float4
    float* oy = out + 8192 * 128;
    if (q < 2) {                    // rows q*4+r in [0,8) only
#pragma unroll
      for (int j = 0; j < 2; ++j)
#pragma unroll
        for (int r = 0; r < 4; ++r)
          oy[(blockRow + q * 4 + r) * 128 + ncol[j]] = yr[j][r];
    }
  }
}

extern "C" void kernel_launch(void* const* d_in, const int* in_sizes, int n_in,
                              void* d_out, int out_size, void* d_ws, size_t ws_size,
                              hipStream_t stream) {
  const float* t  = (const float*)d_in[0];
  const float* x  = (const float*)d_in[1];
  const float* W1 = (const float*)d_in[2];
  const float* b1 = (const float*)d_in[3];
  const float* W2 = (const float*)d_in[4];
  const float* b2 = (const float*)d_in[5];
  float* out = (float*)d_out;
  node_kernel<<<dim3(1024), dim3(256), 0, stream>>>(t, x, W1, b1, W2, b2, out);
}

// Round 11
// 210.738 us; speedup vs baseline: 2.6321x; 2.6321x over previous
//
#include <hip/hip_runtime.h>

// NeuralODE: y' = tanh(y@W1+b1)@W2+b2, fixed-step Dopri5, <=48 static iters.
// R12: R11's redundant-compute overlap (8-output-row blocks computing 16 rows,
// grid 1024 -> 4 blocks/CU) with the launch_bounds bug fixed: (256,2) as in
// R7b, NOT (256,4). R11's (256,4) forced the allocator to 64 VGPR -> spilled
// weight frags + k-state to scratch -> 1.8GB HBM traffic/dispatch, 502us.
// With (256,2) the kernel compiles exactly like R7b (96 VGPR, no spill) and
// the HW still fits 4 blocks/CU (21 waves/CU at 96 VGPR). Eval body = R7b
// exactly (R9/R10 proved it locally optimal).

typedef __attribute__((ext_vector_type(8))) short short8;  // 8 bf16 = 4 VGPRs
typedef __attribute__((ext_vector_type(4))) float f32x4;

#define SL 136  // LDS row stride in bf16: 272B = 16B-aligned rows (b128 reads)

__device__ __forceinline__ short f2bf(float f) {
  union { float f; unsigned u; } v; v.f = f;
  return (short)((v.u + 0x8000u) >> 16);  // for weight load only (not hot)
}

__device__ __forceinline__ float fast_tanh(float x) {
  // tanh(x) = 1 - 2/(exp2(c*x)+1), c = 2*log2(e). 5 VALU ops, exact at +-inf.
  float e = __builtin_amdgcn_exp2f(x * 2.88539008177793f);
  float r = __builtin_amdgcn_rcpf(e + 1.0f);
  return __builtin_fmaf(-2.0f, r, 1.0f);
}

// pack 2 f32 -> 2 bf16 in one instr; store lo/hi halves to two LDS addrs
// (compiler folds the hi store to ds_write_b16_d16_hi).
__device__ __forceinline__ void store_bf16_pair(short* p0, short* p1,
                                                float a, float b) {
  unsigned u;
  asm("v_cvt_pk_bf16_f32 %0, %1, %2" : "=v"(u) : "v"(a), "v"(b));
  *p0 = (short)(u & 0xffffu);
  *p1 = (short)(u >> 16);
}

__global__ __launch_bounds__(256, 2)
void node_kernel(const float* __restrict__ tptr, const float* __restrict__ x,
                 const float* __restrict__ W1, const float* __restrict__ b1,
                 const float* __restrict__ W2, const float* __restrict__ b2,
                 float* __restrict__ out) {
  const int tid  = threadIdx.x;
  const int wv   = tid >> 6;      // wave id (0..3); wave owns col-tiles 2wv,2wv+1
  const int lane = tid & 63;
  const int q    = lane >> 4;     // quad within wave
  const int colL = lane & 15;     // col within tile (C layout) / m row (A frag)
  const int blockRow = blockIdx.x * 8;   // 8 OUTPUT rows; computes 16

  __shared__ short A1[16][SL];   // staged y' (bf16, A-operand layout)
  __shared__ short A2[16][SL];   // staged tanh hidden (bf16)
  __shared__ float sred[256];

  // ---------- weight B-fragments (bf16) + biases into registers ----------
  // B-frag 16x16x32: lane holds B[k = kt*32 + quad*8 + i][n], i=0..7.
  short8 w1f[2][4], w2f[2][4];
  float b1v[2], b2v[2];
  int ncol[2];
#pragma unroll
  for (int j = 0; j < 2; ++j) {
    const int n = (2 * wv + j) * 16 + colL;
    ncol[j] = n;
    b1v[j] = b1[n]; b2v[j] = b2[n];
#pragma unroll
    for (int kt = 0; kt < 4; ++kt) {
      short8 v1, v2;
#pragma unroll
      for (int i = 0; i < 8; ++i) {
        const int k = kt * 32 + q * 8 + i;
        v1[i] = f2bf(W1[k * 128 + n]);
        v2[i] = f2bf(W2[k * 128 + n]);
      }
      w1f[j][kt] = v1; w2f[j][kt] = v2;
    }
  }

  // ---------- block-wide sum (256 threads) ----------
  auto block_sum = [&](float v) -> float {
    sred[tid] = v;
    __syncthreads();
    if (tid < 64) {
      float s = sred[tid] + sred[tid + 64] + sred[tid + 128] + sred[tid + 192];
#pragma unroll
      for (int o = 32; o > 0; o >>= 1) s += __shfl_down(s, o, 64);
      if (tid == 0) sred[0] = s;
    }
    __syncthreads();
    float r = sred[0];
    __syncthreads();
    return r;
  };

  // hoisted LDS addresses (constant immediate offsets thereafter)
  short* const wr1 = &A1[q * 4][0];
  short* const wr2 = &A2[q * 4][0];
  const short* const rd1 = &A1[colL][q * 8];
  const short* const rd2 = &A2[colL][q * 8];

  // ---------- one f-eval: LDS round-trip transpose + 2 MFMA layers ----------
  auto evalF = [&](auto&& gen, f32x4 (&fout)[2]) {
#pragma unroll
    for (int j = 0; j < 2; ++j) {
      f32x4 v = gen(j);
      store_bf16_pair(&wr1[0 * SL + ncol[j]], &wr1[1 * SL + ncol[j]], v[0], v[1]);
      store_bf16_pair(&wr1[2 * SL + ncol[j]], &wr1[3 * SL + ncol[j]], v[2], v[3]);
    }
    __syncthreads();
    short8 af[4];
#pragma unroll
    for (int kt = 0; kt < 4; ++kt) af[kt] = *(const short8*)(rd1 + kt * 32);
    f32x4 acc0 = {b1v[0], b1v[0], b1v[0], b1v[0]};
    f32x4 acc1 = {b1v[1], b1v[1], b1v[1], b1v[1]};
    __builtin_amdgcn_s_setprio(1);
#pragma unroll
    for (int kt = 0; kt < 4; ++kt) {
      acc0 = __builtin_amdgcn_mfma_f32_16x16x32_bf16(af[kt], w1f[0][kt], acc0, 0, 0, 0);
      acc1 = __builtin_amdgcn_mfma_f32_16x16x32_bf16(af[kt], w1f[1][kt], acc1, 0, 0, 0);
    }
    __builtin_amdgcn_s_setprio(0);
    {
      float h0a = fast_tanh(acc0[0]), h1a = fast_tanh(acc0[1]);
      float h2a = fast_tanh(acc0[2]), h3a = fast_tanh(acc0[3]);
      store_bf16_pair(&wr2[0 * SL + ncol[0]], &wr2[1 * SL + ncol[0]], h0a, h1a);
      store_bf16_pair(&wr2[2 * SL + ncol[0]], &wr2[3 * SL + ncol[0]], h2a, h3a);
      float h0b = fast_tanh(acc1[0]), h1b = fast_tanh(acc1[1]);
      float h2b = fast_tanh(acc1[2]), h3b = fast_tanh(acc1[3]);
      store_bf16_pair(&wr2[0 * SL + ncol[1]], &wr2[1 * SL + ncol[1]], h0b, h1b);
      store_bf16_pair(&wr2[2 * SL + ncol[1]], &wr2[3 * SL + ncol[1]], h2b, h3b);
    }
    __syncthreads();
#pragma unroll
    for (int kt = 0; kt < 4; ++kt) af[kt] = *(const short8*)(rd2 + kt * 32);
    f32x4 f0 = {b2v[0], b2v[0], b2v[0], b2v[0]};
    f32x4 f1 = {b2v[1], b2v[1], b2v[1], b2v[1]};
    __builtin_amdgcn_s_setprio(1);
#pragma unroll
    for (int kt = 0; kt < 4; ++kt) {
      f0 = __builtin_amdgcn_mfma_f32_16x16x32_bf16(af[kt], w2f[0][kt], f0, 0, 0, 0);
      f1 = __builtin_amdgcn_mfma_f32_16x16x32_bf16(af[kt], w2f[1][kt], f1, 0, 0, 0);
    }
    __builtin_amdgcn_s_setprio(0);
    fout[0] = f0; fout[1] = f1;
  };

  // ---------- dt0 via the MFMA evalF on row-0-broadcast state ----------
  float y0j[2], scl[2];
#pragma unroll
  for (int j = 0; j < 2; ++j) {
    y0j[j] = x[ncol[j]];
    scl[j] = 1.4e-8f + fabsf(y0j[j]) * 1.4e-8f;
  }
  f32x4 fb[2];
  evalF([&](int j) { float v = y0j[j]; return (f32x4){v, v, v, v}; }, fb);
  float f0j[2] = {fb[0][0], fb[1][0]};
  float t0 = 0.f, t1 = 0.f;
  if (q == 0) {
#pragma unroll
    for (int j = 0; j < 2; ++j) {
      float a = y0j[j] / scl[j]; t0 += a * a;
      float b = f0j[j] / scl[j]; t1 += b * b;
    }
  }
  float d0 = sqrtf(block_sum(t0));
  float d1 = sqrtf(block_sum(t1));
  float h0 = (d0 < 1e-5f || d1 < 1e-5f) ? 1e-6f : 0.01f * d0 / d1;
  evalF([&](int j) { float v = y0j[j] + h0 * f0j[j]; return (f32x4){v, v, v, v}; }, fb);
  float t2 = 0.f;
  if (q == 0) {
#pragma unroll
    for (int j = 0; j < 2; ++j) {
      float a = (fb[j][0] - f0j[j]) / scl[j]; t2 += a * a;
    }
  }
  float d2 = sqrtf(block_sum(t2)) / h0;
  float h1 = (d1 <= 1e-15f && d2 <= 1e-15f) ? fmaxf(1e-6f, h0 * 1e-3f)
                                            : powf(0.01f / (d1 + d2), 0.2f);
  const float dt0v = fminf(100.f * h0, h1);

  // ---------- load state y (rows clamped; upper 8 rows are redundant) ------
  f32x4 yr[2];
#pragma unroll
  for (int j = 0; j < 2; ++j)
#pragma unroll
    for (int r = 0; r < 4; ++r) {
      int row = blockRow + q * 4 + r;
      row = row < 8191 ? row : 8191;
      yr[j][r] = x[row * 128 + ncol[j]];
    }

  // ---------- main fixed-step Dopri5 loop ----------
  const float T = tptr[0] / 10.0f;  // t[0] / TIMESCALE
  float tt = 0.f;
  f32x4 k1[2], k2[2], k3[2], k4[2], k5[2], k6[2];

#pragma unroll 1
  for (int it = 0; it < 48; ++it) {
    float dt = fminf(fmaxf(T - tt, 0.f), dt0v);
    if (dt <= 0.f) break;  // uniform across threads and blocks; tt only grows
    evalF([&](int j) { return yr[j]; }, k1);
    {
      const float c1 = dt * 0.2f;
      evalF([&](int j) { return yr[j] + c1 * k1[j]; }, k2);
    }
    {
      const float c1 = dt * 0.075f, c2 = dt * 0.225f;
      evalF([&](int j) { return yr[j] + c1 * k1[j] + c2 * k2[j]; }, k3);
    }
    {
      const float c1 = dt * 0.9777777777777777f, c2 = dt * -3.7333333333333334f,
                  c3 = dt * 3.5555555555555554f;
      evalF([&](int j) { return yr[j] + c1 * k1[j] + c2 * k2[j] + c3 * k3[j]; }, k4);
    }
    {
      const float c1 = dt * 2.9525986892242035f, c2 = dt * -11.595793324188385f,
                  c3 = dt * 9.822892851699436f, c4 = dt * -0.2908093278463649f;
      evalF([&](int j) {
        return yr[j] + c1 * k1[j] + c2 * k2[j] + c3 * k3[j] + c4 * k4[j];
      }, k5);
    }
    {
      const float c1 = dt * 2.8462752525252526f, c2 = dt * -10.757575757575758f,
                  c3 = dt * 8.906422717743473f, c4 = dt * 0.2784090909090909f,
                  c5 = dt * -0.27351165254237287f;
      evalF([&](int j) {
        return yr[j] + c1 * k1[j] + c2 * k2[j] + c3 * k3[j] + c4 * k4[j]
                     + c5 * k5[j];
      }, k6);
    }
    {
      const float c1 = dt * 0.0911458333333333f, c3 = dt * 0.449236298292902f,
                  c4 = dt * 0.6510416666666666f, c5 = dt * -0.32237617924528303f,
                  c6 = dt * 0.13095238095238096f;
#pragma unroll
      for (int j = 0; j < 2; ++j)
        yr[j] = yr[j] + c1 * k1[j] + c3 * k3[j] + c4 * k4[j] + c5 * k5[j]
                      + c6 * k6[j];
    }
    tt += dt;
  }

  // ---------- epilogue: out = stack([x, yT]) -- 8 output rows ----------
  {
    const float4* x4 = (const float4*)(x + blockRow * 128);
    float4* o4 = (float4*)(out + blockRow * 128);
    o4[tid] = x4[tid];              // 8 rows * 128 f32 = 256 float4
    float* oy = out + 8192 * 128;
    if (q < 2) {                    // rows q*4+r in [0,8) only
#pragma unroll
      for (int j = 0; j < 2; ++j)
#pragma unroll
        for (int r = 0; r < 4; ++r)
          oy[(blockRow + q * 4 + r) * 128 + ncol[j]] = yr[j][r];
    }
  }
}

extern "C" void kernel_launch(void* const* d_in, const int* in_sizes, int n_in,
                              void* d_out, int out_size, void* d_ws, size_t ws_size,
                              hipStream_t stream) {
  const float* t  = (const float*)d_in[0];
  const float* x  = (const float*)d_in[1];
  const float* W1 = (const float*)d_in[2];
  const float* b1 = (const float*)d_in[3];
  const float* W2 = (const float*)d_in[4];
  const float* b2 = (const float*)d_in[5];
  float* out = (float*)d_out;
  node_kernel<<<dim3(1024), dim3(256), 0, stream>>>(t, x, W1, b1, W2, b2, out);
}

// Round 12
// 138.941 us; speedup vs baseline: 3.9923x; 1.5167x over previous
//
#include <hip/hip_runtime.h>

// NeuralODE: y' = tanh(y@W1+b1)@W2+b2, fixed-step Dopri5, <=48 static iters.
// R13: restore R7b exactly (best verified: 87us kernel-time) -- R8..R12 all
// regressed and are reverted. Structure: 4 waves x 2 col-tiles, 16 rows/block,
// grid 512 -> 2 blocks/CU, weights as register B-frags, [16][SL] row-major
// staging (b16-pair writes, b128 frag reads, both at bank minimum),
// 2 barriers/eval (minimal RAW transposes), exp2-tanh, MFMA-based dt0.
// One tweak vs R7b: the out[0:B]=x copy is issued BEFORE the main loop so its
// HBM traffic drains under the ~80us of compute instead of serializing at
// block retirement. Known-blocked levers (measured): eval body (R9/R10),
// write-path conflicts (R9: counter unchanged), co-residency (R12: 2
// blocks/CU reg-capped), redundant compute (util ~60%, no free slots).

typedef __attribute__((ext_vector_type(8))) short short8;  // 8 bf16 = 4 VGPRs
typedef __attribute__((ext_vector_type(4))) float f32x4;

#define SL 136  // LDS row stride in bf16: 272B = 16B-aligned rows (b128 reads)

__device__ __forceinline__ short f2bf(float f) {
  union { float f; unsigned u; } v; v.f = f;
  return (short)((v.u + 0x8000u) >> 16);  // for weight load only (not hot)
}

__device__ __forceinline__ float fast_tanh(float x) {
  // tanh(x) = 1 - 2/(exp2(c*x)+1), c = 2*log2(e). 5 VALU ops, exact at +-inf.
  float e = __builtin_amdgcn_exp2f(x * 2.88539008177793f);
  float r = __builtin_amdgcn_rcpf(e + 1.0f);
  return __builtin_fmaf(-2.0f, r, 1.0f);
}

// pack 2 f32 -> 2 bf16 in one instr; store lo/hi halves to two LDS addrs
// (compiler folds the hi store to ds_write_b16_d16_hi).
__device__ __forceinline__ void store_bf16_pair(short* p0, short* p1,
                                                float a, float b) {
  unsigned u;
  asm("v_cvt_pk_bf16_f32 %0, %1, %2" : "=v"(u) : "v"(a), "v"(b));
  *p0 = (short)(u & 0xffffu);
  *p1 = (short)(u >> 16);
}

__global__ __launch_bounds__(256, 2)
void node_kernel(const float* __restrict__ tptr, const float* __restrict__ x,
                 const float* __restrict__ W1, const float* __restrict__ b1,
                 const float* __restrict__ W2, const float* __restrict__ b2,
                 float* __restrict__ out) {
  const int tid  = threadIdx.x;
  const int wv   = tid >> 6;      // wave id (0..3); wave owns col-tiles 2wv,2wv+1
  const int lane = tid & 63;
  const int q    = lane >> 4;     // quad within wave
  const int colL = lane & 15;     // col within tile (C layout) / m row (A frag)
  const int blockRow = blockIdx.x * 16;

  __shared__ short A1[16][SL];   // staged y' (bf16, A-operand layout)
  __shared__ short A2[16][SL];   // staged tanh hidden (bf16)
  __shared__ float sred[256];

  // ---------- early epilogue part 1: out[0:B] = x (drains under compute) ----
  {
    const float4* x4 = (const float4*)(x + blockRow * 128);
    float4* o4 = (float4*)(out + blockRow * 128);
    o4[tid] = x4[tid];              // 16 rows * 128 f32 = 512 float4
    o4[tid + 256] = x4[tid + 256];
  }

  // ---------- weight B-fragments (bf16) + biases into registers ----------
  // B-frag 16x16x32: lane holds B[k = kt*32 + quad*8 + i][n], i=0..7.
  short8 w1f[2][4], w2f[2][4];
  float b1v[2], b2v[2];
  int ncol[2];
#pragma unroll
  for (int j = 0; j < 2; ++j) {
    const int n = (2 * wv + j) * 16 + colL;
    ncol[j] = n;
    b1v[j] = b1[n]; b2v[j] = b2[n];
#pragma unroll
    for (int kt = 0; kt < 4; ++kt) {
      short8 v1, v2;
#pragma unroll
      for (int i = 0; i < 8; ++i) {
        const int k = kt * 32 + q * 8 + i;
        v1[i] = f2bf(W1[k * 128 + n]);
        v2[i] = f2bf(W2[k * 128 + n]);
      }
      w1f[j][kt] = v1; w2f[j][kt] = v2;
    }
  }

  // ---------- block-wide sum (256 threads) ----------
  auto block_sum = [&](float v) -> float {
    sred[tid] = v;
    __syncthreads();
    if (tid < 64) {
      float s = sred[tid] + sred[tid + 64] + sred[tid + 128] + sred[tid + 192];
#pragma unroll
      for (int o = 32; o > 0; o >>= 1) s += __shfl_down(s, o, 64);
      if (tid == 0) sred[0] = s;
    }
    __syncthreads();
    float r = sred[0];
    __syncthreads();
    return r;
  };

  // hoisted LDS addresses (constant immediate offsets thereafter)
  short* const wr1 = &A1[q * 4][0];
  short* const wr2 = &A2[q * 4][0];
  const short* const rd1 = &A1[colL][q * 8];
  const short* const rd2 = &A2[colL][q * 8];

  // ---------- one f-eval: LDS round-trip transpose + 2 MFMA layers ----------
  auto evalF = [&](auto&& gen, f32x4 (&fout)[2]) {
#pragma unroll
    for (int j = 0; j < 2; ++j) {
      f32x4 v = gen(j);
      store_bf16_pair(&wr1[0 * SL + ncol[j]], &wr1[1 * SL + ncol[j]], v[0], v[1]);
      store_bf16_pair(&wr1[2 * SL + ncol[j]], &wr1[3 * SL + ncol[j]], v[2], v[3]);
    }
    __syncthreads();
    short8 af[4];
#pragma unroll
    for (int kt = 0; kt < 4; ++kt) af[kt] = *(const short8*)(rd1 + kt * 32);
    f32x4 acc0 = {b1v[0], b1v[0], b1v[0], b1v[0]};
    f32x4 acc1 = {b1v[1], b1v[1], b1v[1], b1v[1]};
    __builtin_amdgcn_s_setprio(1);
#pragma unroll
    for (int kt = 0; kt < 4; ++kt) {
      acc0 = __builtin_amdgcn_mfma_f32_16x16x32_bf16(af[kt], w1f[0][kt], acc0, 0, 0, 0);
      acc1 = __builtin_amdgcn_mfma_f32_16x16x32_bf16(af[kt], w1f[1][kt], acc1, 0, 0, 0);
    }
    __builtin_amdgcn_s_setprio(0);
    {
      float h0a = fast_tanh(acc0[0]), h1a = fast_tanh(acc0[1]);
      float h2a = fast_tanh(acc0[2]), h3a = fast_tanh(acc0[3]);
      store_bf16_pair(&wr2[0 * SL + ncol[0]], &wr2[1 * SL + ncol[0]], h0a, h1a);
      store_bf16_pair(&wr2[2 * SL + ncol[0]], &wr2[3 * SL + ncol[0]], h2a, h3a);
      float h0b = fast_tanh(acc1[0]), h1b = fast_tanh(acc1[1]);
      float h2b = fast_tanh(acc1[2]), h3b = fast_tanh(acc1[3]);
      store_bf16_pair(&wr2[0 * SL + ncol[1]], &wr2[1 * SL + ncol[1]], h0b, h1b);
      store_bf16_pair(&wr2[2 * SL + ncol[1]], &wr2[3 * SL + ncol[1]], h2b, h3b);
    }
    __syncthreads();
#pragma unroll
    for (int kt = 0; kt < 4; ++kt) af[kt] = *(const short8*)(rd2 + kt * 32);
    f32x4 f0 = {b2v[0], b2v[0], b2v[0], b2v[0]};
    f32x4 f1 = {b2v[1], b2v[1], b2v[1], b2v[1]};
    __builtin_amdgcn_s_setprio(1);
#pragma unroll
    for (int kt = 0; kt < 4; ++kt) {
      f0 = __builtin_amdgcn_mfma_f32_16x16x32_bf16(af[kt], w2f[0][kt], f0, 0, 0, 0);
      f1 = __builtin_amdgcn_mfma_f32_16x16x32_bf16(af[kt], w2f[1][kt], f1, 0, 0, 0);
    }
    __builtin_amdgcn_s_setprio(0);
    fout[0] = f0; fout[1] = f1;
  };

  // ---------- dt0 via the MFMA evalF on row-0-broadcast state ----------
  float y0j[2], scl[2];
#pragma unroll
  for (int j = 0; j < 2; ++j) {
    y0j[j] = x[ncol[j]];
    scl[j] = 1.4e-8f + fabsf(y0j[j]) * 1.4e-8f;
  }
  f32x4 fb[2];
  evalF([&](int j) { float v = y0j[j]; return (f32x4){v, v, v, v}; }, fb);
  float f0j[2] = {fb[0][0], fb[1][0]};
  float t0 = 0.f, t1 = 0.f;
  if (q == 0) {
#pragma unroll
    for (int j = 0; j < 2; ++j) {
      float a = y0j[j] / scl[j]; t0 += a * a;
      float b = f0j[j] / scl[j]; t1 += b * b;
    }
  }
  float d0 = sqrtf(block_sum(t0));
  float d1 = sqrtf(block_sum(t1));
  float h0 = (d0 < 1e-5f || d1 < 1e-5f) ? 1e-6f : 0.01f * d0 / d1;
  evalF([&](int j) { float v = y0j[j] + h0 * f0j[j]; return (f32x4){v, v, v, v}; }, fb);
  float t2 = 0.f;
  if (q == 0) {
#pragma unroll
    for (int j = 0; j < 2; ++j) {
      float a = (fb[j][0] - f0j[j]) / scl[j]; t2 += a * a;
    }
  }
  float d2 = sqrtf(block_sum(t2)) / h0;
  float h1 = (d1 <= 1e-15f && d2 <= 1e-15f) ? fmaxf(1e-6f, h0 * 1e-3f)
                                            : powf(0.01f / (d1 + d2), 0.2f);
  const float dt0v = fminf(100.f * h0, h1);

  // ---------- load state y (C-layout: rows q*4+r, cols ncol[j]) ----------
  f32x4 yr[2];
#pragma unroll
  for (int j = 0; j < 2; ++j)
#pragma unroll
    for (int r = 0; r < 4; ++r)
      yr[j][r] = x[(blockRow + q * 4 + r) * 128 + ncol[j]];

  // ---------- main fixed-step Dopri5 loop ----------
  const float T = tptr[0] / 10.0f;  // t[0] / TIMESCALE
  float tt = 0.f;
  f32x4 k1[2], k2[2], k3[2], k4[2], k5[2], k6[2];

#pragma unroll 1
  for (int it = 0; it < 48; ++it) {
    float dt = fminf(fmaxf(T - tt, 0.f), dt0v);
    if (dt <= 0.f) break;  // uniform across threads and blocks; tt only grows
    evalF([&](int j) { return yr[j]; }, k1);
    {
      const float c1 = dt * 0.2f;
      evalF([&](int j) { return yr[j] + c1 * k1[j]; }, k2);
    }
    {
      const float c1 = dt * 0.075f, c2 = dt * 0.225f;
      evalF([&](int j) { return yr[j] + c1 * k1[j] + c2 * k2[j]; }, k3);
    }
    {
      const float c1 = dt * 0.9777777777777777f, c2 = dt * -3.7333333333333334f,
                  c3 = dt * 3.5555555555555554f;
      evalF([&](int j) { return yr[j] + c1 * k1[j] + c2 * k2[j] + c3 * k3[j]; }, k4);
    }
    {
      const float c1 = dt * 2.9525986892242035f, c2 = dt * -11.595793324188385f,
                  c3 = dt * 9.822892851699436f, c4 = dt * -0.2908093278463649f;
      evalF([&](int j) {
        return yr[j] + c1 * k1[j] + c2 * k2[j] + c3 * k3[j] + c4 * k4[j];
      }, k5);
    }
    {
      const float c1 = dt * 2.8462752525252526f, c2 = dt * -10.757575757575758f,
                  c3 = dt * 8.906422717743473f, c4 = dt * 0.2784090909090909f,
                  c5 = dt * -0.27351165254237287f;
      evalF([&](int j) {
        return yr[j] + c1 * k1[j] + c2 * k2[j] + c3 * k3[j] + c4 * k4[j]
                     + c5 * k5[j];
      }, k6);
    }
    {
      const float c1 = dt * 0.0911458333333333f, c3 = dt * 0.449236298292902f,
                  c4 = dt * 0.6510416666666666f, c5 = dt * -0.32237617924528303f,
                  c6 = dt * 0.13095238095238096f;
#pragma unroll
      for (int j = 0; j < 2; ++j)
        yr[j] = yr[j] + c1 * k1[j] + c3 * k3[j] + c4 * k4[j] + c5 * k5[j]
                      + c6 * k6[j];
    }
    tt += dt;
  }

  // ---------- epilogue part 2: out[B:2B] = yT ----------
  {
    float* oy = out + 8192 * 128;
#pragma unroll
    for (int j = 0; j < 2; ++j)
#pragma unroll
      for (int r = 0; r < 4; ++r)
        oy[(blockRow + q * 4 + r) * 128 + ncol[j]] = yr[j][r];
  }
}

extern "C" void kernel_launch(void* const* d_in, const int* in_sizes, int n_in,
                              void* d_out, int out_size, void* d_ws, size_t ws_size,
                              hipStream_t stream) {
  const float* t  = (const float*)d_in[0];
  const float* x  = (const float*)d_in[1];
  const float* W1 = (const float*)d_in[2];
  const float* b1 = (const float*)d_in[3];
  const float* W2 = (const float*)d_in[4];
  const float* b2 = (const float*)d_in[5];
  float* out = (float*)d_out;
  node_kernel<<<dim3(512), dim3(256), 0, stream>>>(t, x, W1, b1, W2, b2, out);
}